// Round 7
// baseline (953.122 us; speedup 1.0000x reference)
//
#include <hip/hip_runtime.h>
#include <stdint.h>

typedef __attribute__((ext_vector_type(8))) short short8;
typedef __attribute__((ext_vector_type(4))) float f32x4;
typedef __attribute__((ext_vector_type(4))) unsigned short us4;

__device__ __forceinline__ unsigned short f2bf(float f) {
  union { float f; unsigned int i; } v; v.f = f;
  unsigned int r = (v.i + 0x7FFFu + ((v.i >> 16) & 1u)) >> 16;
  return (unsigned short)r;
}
__device__ __forceinline__ float hswish(float x) {
  float t = fminf(fmaxf(x + 3.f, 0.f), 6.f);
  return x * t * (1.f / 6.f);
}

// ---------------------------------------------------------------------------
// Prep: pack conv weights (and optionally tril-masked L mats + M1 transpose)
// into per-lane-contiguous MFMA fragment order.
//   cwP_s[((ot*NKS + ks)*64 + lane)*8 + e] = bf16(cw_s[o][i][j])
//   Lb packed identically over (t-tile, ks) so a TM a-fragment is one
//   coalesced 16B load.  M1T[n*64+r] = M1[r*4096+n].
// ---------------------------------------------------------------------------
__device__ __forceinline__ void cwprep(const float* __restrict__ cw,
                                       unsigned short* __restrict__ dst,
                                       int rel, int k, int NKS) {
  int e = rel & 7;
  int lane = (rel >> 3) & 63;
  int rest = rel >> 9;
  int ksl = rest % NKS, ot = rest / NKS;
  int m = ksl * 32 + (lane >> 4) * 8 + e;
  int o = ot * 16 + (lane & 15);
  int j = m >> 7, i = m & 127;
  dst[rel] = f2bf(cw[(o * 128 + i) * k + j]);
}

__device__ __forceinline__ void lbprep(const float* __restrict__ L,
                                       unsigned short* __restrict__ dst,
                                       int rel, int TK) {
  int NTS = TK / 32;
  int e = rel & 7;
  int lane = (rel >> 3) & 63;
  int rest = rel >> 9;
  int ks = rest % NTS, tt = rest / NTS;
  int trow = tt * 16 + (lane & 15);
  int col = ks * 32 + (lane >> 4) * 8 + e;
  dst[rel] = (col <= trow) ? f2bf(L[trow * TK + col]) : (unsigned short)0;
}

__global__ void prep_kernel(const float* __restrict__ cw0,
                            const float* __restrict__ cw1,
                            const float* __restrict__ cw2,
                            const float* __restrict__ L1_0, const float* __restrict__ L2_0,
                            const float* __restrict__ L1_1, const float* __restrict__ L2_1,
                            const float* __restrict__ L1_2, const float* __restrict__ L2_2,
                            const float* __restrict__ M1,
                            unsigned short* __restrict__ cwP0,
                            unsigned short* __restrict__ cwP1,
                            unsigned short* __restrict__ cwP2,
                            unsigned short* __restrict__ Lb,     // may be null
                            float* __restrict__ M1T) {           // may be null
  int idx = blockIdx.x * 256 + threadIdx.x;
  if (idx < 16384)       { cwprep(cw0, cwP0, idx,          1,  4); return; }
  if (idx < 49152)       { cwprep(cw1, cwP1, idx - 16384,  2,  8); return; }
  if (idx < 114688)      { cwprep(cw2, cwP2, idx - 49152,  4, 16); return; }
  if (Lb == nullptr) return;
  int rel = idx - 114688;
  if (rel < 16384)       { lbprep(L1_0, Lb,          rel,          128); return; }
  if (rel < 32768)       { lbprep(L2_0, Lb + 16384,  rel - 16384,  128); return; }
  if (rel < 36864)       { lbprep(L1_1, Lb + 32768,  rel - 32768,   64); return; }
  if (rel < 40960)       { lbprep(L2_1, Lb + 36864,  rel - 36864,   64); return; }
  if (rel < 41984)       { lbprep(L1_2, Lb + 40960,  rel - 40960,   32); return; }
  if (rel < 43008)       { lbprep(L2_2, Lb + 41984,  rel - 41984,   32); return; }
  int t = rel - 43008;
  if (t < 262144) M1T[t] = M1[(t & 63) * 4096 + (t >> 6)];
}

// ---------------------------------------------------------------------------
// L-matrix fragment fallback: gather 8 fp32, tril-mask, convert to bf16.
// ---------------------------------------------------------------------------
__device__ __forceinline__ short8 lfrag(const float* __restrict__ L, int TK,
                                        int srow, int scol) {
  const float4 v0 = *(const float4*)(L + srow * TK + scol);
  const float4 v1 = *(const float4*)(L + srow * TK + scol + 4);
  short8 r;
  r[0] = (scol     <= srow) ? (short)f2bf(v0.x) : (short)0;
  r[1] = (scol + 1 <= srow) ? (short)f2bf(v0.y) : (short)0;
  r[2] = (scol + 2 <= srow) ? (short)f2bf(v0.z) : (short)0;
  r[3] = (scol + 3 <= srow) ? (short)f2bf(v0.w) : (short)0;
  r[4] = (scol + 4 <= srow) ? (short)f2bf(v1.x) : (short)0;
  r[5] = (scol + 5 <= srow) ? (short)f2bf(v1.y) : (short)0;
  r[6] = (scol + 6 <= srow) ? (short)f2bf(v1.z) : (short)0;
  r[7] = (scol + 7 <= srow) ? (short)f2bf(v1.w) : (short)0;
  return r;
}

// ---------------------------------------------------------------------------
// Conv, o-ownership: each wave owns 2 o-tiles, loops over all t-tiles.
// ---------------------------------------------------------------------------
template <int S, int nTT>
__device__ __forceinline__ void conv_o(const unsigned short* __restrict__ xb,
                                       const unsigned short* __restrict__ cwP,
                                       f32x4 (&acc)[nTT][2],
                                       int wave, int lane, int quad, int l16) {
  constexpr int NKS = (128 << S) / 32;
#pragma unroll
  for (int tt = 0; tt < nTT; ++tt)
#pragma unroll
    for (int oo = 0; oo < 2; ++oo)
      acc[tt][oo] = (f32x4){0.f, 0.f, 0.f, 0.f};

#pragma unroll
  for (int ks = 0; ks < NKS; ++ks) {
    const int m = ks * 32 + quad * 8;
    short8 a[nTT];
#pragma unroll
    for (int tt = 0; tt < nTT; ++tt) {
      int t = tt * 16 + l16;
      a[tt] = *(const short8*)&xb[((t << S) + (m >> 7)) * 136 + (m & 127)];
    }
#pragma unroll
    for (int oo = 0; oo < 2; ++oo) {
      const short8 b = *(const short8*)&cwP[(((wave * 2 + oo) * NKS + ks) * 64 + lane) * 8];
#pragma unroll
      for (int tt = 0; tt < nTT; ++tt)
        acc[tt][oo] = __builtin_amdgcn_mfma_f32_16x16x32_bf16(a[tt], b, acc[tt][oo], 0, 0, 0);
    }
  }
}

// ---------------------------------------------------------------------------
// Post (single scale): +cb -> LN -> fc#1 -> HT -> TM1 -> UT -> TM2 -> fc#2.
// PK: use prep-packed L fragments (one 16B coalesced load) vs lfrag gather.
// HT/UT writes packed as us4 (4 consecutive t per store).
// scratch: [0,128) fcw; [128,352) part; [352,360) red
// ---------------------------------------------------------------------------
template <int S, int nTT, bool PK>
__device__ __forceinline__ void post_o(unsigned short* __restrict__ HT,
                                       float* __restrict__ scratch,
                                       f32x4 (&acc)[nTT][2],
                                       const float* __restrict__ cb,
                                       const float* __restrict__ lg,
                                       const float* __restrict__ lb,
                                       const float* __restrict__ L1,
                                       const float* __restrict__ L2,
                                       const unsigned short* __restrict__ L1p,
                                       const unsigned short* __restrict__ L2p,
                                       int tid, int wave, int lane,
                                       int quad, int l16) {
  constexpr int TK    = 128 >> S;
  constexpr int OFF   = (S == 0) ? 0 : (S == 1 ? 128 : 192);
  constexpr int NTS   = TK / 32;
  constexpr int HTP   = TK + 8;
  constexpr int nTOwn = (S == 0) ? 2 : 1;
  constexpr int nFF   = (S == 2) ? 4 : 8;
  const int ffBase  = (S == 2) ? ((wave >> 1) * 4) : 0;
  const int maxTown = (S == 0) ? (wave + 4) : ((S == 1) ? wave : (wave & 1));

  // ---- +cb, LN stats ----
  float sum = 0.f, ss = 0.f;
#pragma unroll
  for (int oo = 0; oo < 2; ++oo) {
    float cbv = cb[(wave * 2 + oo) * 16 + l16];
#pragma unroll
    for (int tt = 0; tt < nTT; ++tt)
#pragma unroll
      for (int r = 0; r < 4; ++r) {
        float v = acc[tt][oo][r] + cbv;
        acc[tt][oo][r] = v;
        sum += v; ss += v * v;
      }
  }
#pragma unroll
  for (int m = 32; m >= 1; m >>= 1) {
    sum += __shfl_xor(sum, m);
    ss  += __shfl_xor(ss, m);
  }
  if (lane == 0) { scratch[352 + wave * 2] = sum; scratch[353 + wave * 2] = ss; }

  // ---- fc contribution #1 (xt . fcw over own f slice) ----
#pragma unroll
  for (int tt = 0; tt < nTT; ++tt)
#pragma unroll
    for (int r = 0; r < 4; ++r) {
      float v = acc[tt][0][r] * scratch[(wave * 2) * 16 + l16]
              + acc[tt][1][r] * scratch[(wave * 2 + 1) * 16 + l16];
      v += __shfl_xor(v, 1); v += __shfl_xor(v, 2);
      v += __shfl_xor(v, 4); v += __shfl_xor(v, 8);
      if (l16 == 0)
        atomicAdd(&scratch[128 + OFF + tt * 16 + quad * 4 + r], v);
    }
  __syncthreads();

  // every thread finalizes LN stats redundantly (broadcast reads)
  const float Sm = scratch[352] + scratch[354] + scratch[356] + scratch[358];
  const float Sq = scratch[353] + scratch[355] + scratch[357] + scratch[359];
  const float mu = Sm * (1.f / (float)(TK * 128));
  const float rsig = rsqrtf(Sq * (1.f / (float)(TK * 128)) - mu * mu + 1e-5f);

  // ---- HT[f][t] = bf16(LN(h))  (packed us4 stores) ----
#pragma unroll
  for (int oo = 0; oo < 2; ++oo) {
    const int o = (wave * 2 + oo) * 16 + l16;
#pragma unroll
    for (int tt = 0; tt < nTT; ++tt) {
      us4 p;
#pragma unroll
      for (int r = 0; r < 4; ++r) {
        const int t = tt * 16 + quad * 4 + r;
        p[r] = f2bf((acc[tt][oo][r] - mu) * rsig * lg[t * 128 + o] + lb[t * 128 + o]);
      }
      *(us4*)&HT[o * HTP + tt * 16 + quad * 4] = p;
    }
  }
  __syncthreads();   // acc dead; HT visible

  // ---- TM1: U = tril(L1) @ H ----
  f32x4 uacc[nTOwn][nFF];
#pragma unroll
  for (int tt = 0; tt < nTOwn; ++tt)
#pragma unroll
    for (int ff = 0; ff < nFF; ++ff)
      uacc[tt][ff] = (f32x4){0.f, 0.f, 0.f, 0.f};

#pragma unroll
  for (int ks = 0; ks < NTS; ++ks) {
    const int k0 = ks * 32;
    if (k0 <= maxTown * 16 + 15) {
      short8 a[nTOwn];
#pragma unroll
      for (int tt = 0; tt < nTOwn; ++tt) {
        const int tw = (S == 0) ? (wave + tt * 4) : maxTown;
        if (k0 <= tw * 16 + 15) {
          if constexpr (PK)
            a[tt] = *(const short8*)&L1p[((tw * NTS + ks) * 64 + lane) * 8];
          else
            a[tt] = lfrag(L1, TK, tw * 16 + l16, k0 + quad * 8);
        }
      }
#pragma unroll
      for (int ff = 0; ff < nFF; ++ff) {
        const short8 b = *(const short8*)&HT[((ffBase + ff) * 16 + l16) * HTP + k0 + quad * 8];
#pragma unroll
        for (int tt = 0; tt < nTOwn; ++tt) {
          const int tw = (S == 0) ? (wave + tt * 4) : maxTown;
          if (k0 <= tw * 16 + 15)
            uacc[tt][ff] = __builtin_amdgcn_mfma_f32_16x16x32_bf16(a[tt], b, uacc[tt][ff], 0, 0, 0);
        }
      }
    }
  }
  __syncthreads();   // all TM1 HT reads done

  // ---- UT = hswish(U), overwrite HT (packed us4) ----
#pragma unroll
  for (int tt = 0; tt < nTOwn; ++tt) {
    const int tw = (S == 0) ? (wave + tt * 4) : maxTown;
#pragma unroll
    for (int ff = 0; ff < nFF; ++ff) {
      const int f = (ffBase + ff) * 16 + l16;
      us4 p;
#pragma unroll
      for (int r = 0; r < 4; ++r)
        p[r] = f2bf(hswish(uacc[tt][ff][r]));
      *(us4*)&HT[f * HTP + tw * 16 + quad * 4] = p;
    }
  }
  __syncthreads();   // UT visible

  // ---- TM2: v = tril(L2) @ U ----
#pragma unroll
  for (int tt = 0; tt < nTOwn; ++tt)
#pragma unroll
    for (int ff = 0; ff < nFF; ++ff)
      uacc[tt][ff] = (f32x4){0.f, 0.f, 0.f, 0.f};

#pragma unroll
  for (int ks = 0; ks < NTS; ++ks) {
    const int k0 = ks * 32;
    if (k0 <= maxTown * 16 + 15) {
      short8 a[nTOwn];
#pragma unroll
      for (int tt = 0; tt < nTOwn; ++tt) {
        const int tw = (S == 0) ? (wave + tt * 4) : maxTown;
        if (k0 <= tw * 16 + 15) {
          if constexpr (PK)
            a[tt] = *(const short8*)&L2p[((tw * NTS + ks) * 64 + lane) * 8];
          else
            a[tt] = lfrag(L2, TK, tw * 16 + l16, k0 + quad * 8);
        }
      }
#pragma unroll
      for (int ff = 0; ff < nFF; ++ff) {
        const short8 b = *(const short8*)&HT[((ffBase + ff) * 16 + l16) * HTP + k0 + quad * 8];
#pragma unroll
        for (int tt = 0; tt < nTOwn; ++tt) {
          const int tw = (S == 0) ? (wave + tt * 4) : maxTown;
          if (k0 <= tw * 16 + 15)
            uacc[tt][ff] = __builtin_amdgcn_mfma_f32_16x16x32_bf16(a[tt], b, uacc[tt][ff], 0, 0, 0);
        }
      }
    }
  }

  // ---- fc contribution #2 (v . fcw over own f slice, own t) ----
#pragma unroll
  for (int tt = 0; tt < nTOwn; ++tt) {
    const int tw = (S == 0) ? (wave + tt * 4) : maxTown;
#pragma unroll
    for (int r = 0; r < 4; ++r) {
      float v = 0.f;
#pragma unroll
      for (int ff = 0; ff < nFF; ++ff)
        v += uacc[tt][ff][r] * scratch[(ffBase + ff) * 16 + l16];
      v += __shfl_xor(v, 1); v += __shfl_xor(v, 2);
      v += __shfl_xor(v, 4); v += __shfl_xor(v, 8);
      if (l16 == 0)
        atomicAdd(&scratch[128 + OFF + tw * 16 + quad * 4 + r], v);
    }
  }
}

// ---------------------------------------------------------------------------
// Per-scale stage-1 kernel. One sample per block. Only THIS scale's
// accumulators are live -> ~half the register footprint of the fused kernel
// -> 3-4 waves/SIMD occupancy instead of 2 (the round-6 bottleneck).
// Per-scale LN-stat partials decompose the global StockMixing stats.
// ---------------------------------------------------------------------------
template <int S, bool PK>
__launch_bounds__(256, (S == 0) ? 3 : 4)
__global__ void s1s(const float* __restrict__ x,
                    const float* __restrict__ cb, const float* __restrict__ lg,
                    const float* __restrict__ lb,
                    const float* __restrict__ L1, const float* __restrict__ L2,
                    const unsigned short* __restrict__ L1p,
                    const unsigned short* __restrict__ L2p,
                    const float* __restrict__ fc_w, const float* __restrict__ fc_b,
                    const unsigned short* __restrict__ cwP,
                    float* __restrict__ h_out,
                    float* __restrict__ stats) {
  constexpr int TK  = 128 >> S;
  constexpr int OFF = (S == 0) ? 0 : (S == 1 ? 128 : 192);
  constexpr int nTT = 8 >> S;

  extern __shared__ char smem[];
  unsigned short* xb = (unsigned short*)smem;         // 128 x 136 bf16
  float* scratch = (float*)(smem + 34816);

  const int tid  = threadIdx.x;
  const int wave = tid >> 6;
  const int lane = tid & 63;
  const int quad = lane >> 4;
  const int l16  = lane & 15;
  const int n    = blockIdx.x;
  const float* xn = x + (size_t)n * 16384;

  if (tid < 128) scratch[tid] = fc_w[tid];
  if (tid < TK) scratch[128 + OFF + tid] = 0.f;

  // stage x[n] (fp32 -> bf16), one barrier
  for (int i = tid; i < 4096; i += 256) {
    int t = i >> 5, c4 = (i & 31) * 4;
    const float4 v = *(const float4*)(xn + t * 128 + c4);
    us4 p; p[0] = f2bf(v.x); p[1] = f2bf(v.y); p[2] = f2bf(v.z); p[3] = f2bf(v.w);
    *(us4*)&xb[t * 136 + c4] = p;
  }
  __syncthreads();

  f32x4 acc[nTT][2];
  conv_o<S, nTT>(xb, cwP, acc, wave, lane, quad, l16);

  // xb dead after conv (fc#1 barrier precedes first HT write)
  unsigned short* HT = xb;
  post_o<S, nTT, PK>(HT, scratch, acc, cb, lg, lb, L1, L2, L1p, L2p,
                     tid, wave, lane, quad, l16);

  __syncthreads();

  // h slice write + per-scale partial of the global StockMixing-LN stats
  float hv = 0.f;
  if (tid < TK) {
    hv = scratch[128 + OFF + tid] + fc_b[0];
    h_out[(size_t)n * 224 + OFF + tid] = hv;
  }
  float s = hv, sq = hv * hv;
#pragma unroll
  for (int m = 32; m >= 1; m >>= 1) {
    s  += __shfl_xor(s, m);
    sq += __shfl_xor(sq, m);
  }
  __syncthreads();
  if (lane == 0) { scratch[352 + wave * 2] = s; scratch[353 + wave * 2] = sq; }
  __syncthreads();
  if (tid == 0) {
    atomicAdd(&stats[0], scratch[352] + scratch[354] + scratch[356] + scratch[358]);
    atomicAdd(&stats[1], scratch[353] + scratch[355] + scratch[357] + scratch[359]);
  }
}

// ---------------------------------------------------------------------------
// Stage 2.  A is stored TRANSPOSED: A[m*64 + r]  (coalesced write in mix1,
// coalesced read in out).  mix1's M1 read is coalesced via M1T when present.
// ---------------------------------------------------------------------------
template <bool TR>
__global__ void mix1_kernel(const float* __restrict__ h,
                            const float* __restrict__ sm_lg,
                            const float* __restrict__ sm_lb,
                            const float* __restrict__ M1,     // M1T if TR
                            const float* __restrict__ stats,
                            float* __restrict__ A) {
  const int m = blockIdx.x;            // 0..223
  const int seg = blockIdx.y;          // 0..3
  const int r = threadIdx.x & 63;
  const int ch = threadIdx.x >> 6;
  const float inv = 1.f / 917504.f;
  float mu = stats[0] * inv;
  float var = stats[1] * inv - mu * mu;
  float rsig = rsqrtf(var + 1e-5f);
  float a0 = 0.f, a1 = 0.f, a2 = 0.f, a3 = 0.f;
  int n0 = seg * 1024 + ch * 256;
  for (int i = 0; i < 256; i += 4) {
    int n = n0 + i;
    float h0 = (h[(n    ) * 224 + m] - mu) * rsig * sm_lg[(n    ) * 224 + m] + sm_lb[(n    ) * 224 + m];
    float h1 = (h[(n + 1) * 224 + m] - mu) * rsig * sm_lg[(n + 1) * 224 + m] + sm_lb[(n + 1) * 224 + m];
    float h2 = (h[(n + 2) * 224 + m] - mu) * rsig * sm_lg[(n + 2) * 224 + m] + sm_lb[(n + 2) * 224 + m];
    float h3 = (h[(n + 3) * 224 + m] - mu) * rsig * sm_lg[(n + 3) * 224 + m] + sm_lb[(n + 3) * 224 + m];
    if (TR) {
      a0 += M1[(n    ) * 64 + r] * h0;
      a1 += M1[(n + 1) * 64 + r] * h1;
      a2 += M1[(n + 2) * 64 + r] * h2;
      a3 += M1[(n + 3) * 64 + r] * h3;
    } else {
      a0 += M1[r * 4096 + n    ] * h0;
      a1 += M1[r * 4096 + n + 1] * h1;
      a2 += M1[r * 4096 + n + 2] * h2;
      a3 += M1[r * 4096 + n + 3] * h3;
    }
  }
  __shared__ float red[256];
  red[threadIdx.x] = (a0 + a1) + (a2 + a3);
  __syncthreads();
  if (threadIdx.x < 64)
    atomicAdd(&A[m * 64 + threadIdx.x],
              red[threadIdx.x] + red[64 + threadIdx.x] + red[128 + threadIdx.x] + red[192 + threadIdx.x]);
}

// out_kernel with mix2 fused: recompute cvec from transposed A (coalesced).
__global__ void out_kernel(const float* __restrict__ h,
                           const float* __restrict__ A,
                           const float* __restrict__ M2,
                           const float* __restrict__ sm_fc_w,
                           const float* __restrict__ sm_fc_b,
                           float* __restrict__ out) {
  const int tid = threadIdx.x;
  const int wave = tid >> 6, lane = tid & 63;
  __shared__ float red[256];
  __shared__ float cv[64];

  // cvec[r] = sum_j hswish(A[j][r]) * sm_fc_w[224+j]   (A transposed)
  {
    const int r = tid & 63, ch = tid >> 6;
    float acc = 0.f;
    for (int j = ch; j < 224; j += 4)
      acc += hswish(A[j * 64 + r]) * sm_fc_w[224 + j];
    red[tid] = acc;
  }
  __syncthreads();
  if (tid < 64)
    cv[tid] = red[tid] + red[64 + tid] + red[128 + tid] + red[192 + tid];
  __syncthreads();

  const int n = blockIdx.x * 4 + wave;
  float acc = M2[n * 64 + lane] * cv[lane];
  for (int j = lane; j < 224; j += 64)
    acc += h[n * 224 + j] * (sm_fc_w[j] + sm_fc_w[224 + j]);
#pragma unroll
  for (int m = 32; m >= 1; m >>= 1) acc += __shfl_xor(acc, m);
  if (lane == 0) out[n] = acc + sm_fc_b[0];
}

// ---------------------------------------------------------------------------
extern "C" void kernel_launch(void* const* d_in, const int* in_sizes, int n_in,
                              void* d_out, int out_size, void* d_ws, size_t ws_size,
                              hipStream_t stream) {
  const float* x      = (const float*)d_in[0];
  const float* cw0    = (const float*)d_in[1];
  const float* cb0    = (const float*)d_in[2];
  const float* lg0    = (const float*)d_in[3];
  const float* lb0    = (const float*)d_in[4];
  const float* L1_0   = (const float*)d_in[5];
  const float* L2_0   = (const float*)d_in[6];
  const float* cw1    = (const float*)d_in[7];
  const float* cb1    = (const float*)d_in[8];
  const float* lg1    = (const float*)d_in[9];
  const float* lb1    = (const float*)d_in[10];
  const float* L1_1   = (const float*)d_in[11];
  const float* L2_1   = (const float*)d_in[12];
  const float* cw2    = (const float*)d_in[13];
  const float* cb2    = (const float*)d_in[14];
  const float* lg2    = (const float*)d_in[15];
  const float* lb2    = (const float*)d_in[16];
  const float* L1_2   = (const float*)d_in[17];
  const float* L2_2   = (const float*)d_in[18];
  const float* fc_w   = (const float*)d_in[19];
  const float* fc_b   = (const float*)d_in[20];
  const float* sm_lg  = (const float*)d_in[21];
  const float* sm_lb  = (const float*)d_in[22];
  const float* M1     = (const float*)d_in[23];
  const float* M2     = (const float*)d_in[24];
  const float* sm_fc_w = (const float*)d_in[25];
  const float* sm_fc_b = (const float*)d_in[26];

  // Base layout (proven footprint, 3,957,248 B); optional extras gated on ws_size.
  char* ws = (char*)d_ws;
  unsigned short* cwP0 = (unsigned short*)(ws);             // 32768 B
  unsigned short* cwP1 = (unsigned short*)(ws + 32768);     // 65536 B
  unsigned short* cwP2 = (unsigned short*)(ws + 98304);     // 131072 B
  float* h     = (float*)(ws + 229376);                     // 3670016 B
  float* stats = (float*)(ws + 3899392);                    // 8 B
  float* A     = (float*)(ws + 3899648);                    // 57344 B (A^T [224][64])
  const bool extra = ws_size >= 5091840;
  unsigned short* Lb = extra ? (unsigned short*)(ws + 3957248) : nullptr;  // 86016 B
  float* M1T         = extra ? (float*)(ws + 4043264) : nullptr;           // 1048576 B

  prep_kernel<<<1640, 256, 0, stream>>>(cw0, cw1, cw2,
                                        L1_0, L2_0, L1_1, L2_1, L1_2, L2_2, M1,
                                        cwP0, cwP1, cwP2, Lb, M1T);

  // zero stats + A BEFORE s1 (per-scale epilogues atomicAdd into stats)
  hipMemsetAsync(ws + 3899392, 0, 57600, stream);

  constexpr size_t S1_LDS = 34816 + 362 * 4;   // xb/HT union + scratch = 36264 B

  if (extra) {
    s1s<0, true><<<4096, 256, S1_LDS, stream>>>(x, cb0, lg0, lb0, L1_0, L2_0,
        Lb, Lb + 16384, fc_w, fc_b, cwP0, h, stats);
    s1s<1, true><<<4096, 256, S1_LDS, stream>>>(x, cb1, lg1, lb1, L1_1, L2_1,
        Lb + 32768, Lb + 36864, fc_w, fc_b, cwP1, h, stats);
    s1s<2, true><<<4096, 256, S1_LDS, stream>>>(x, cb2, lg2, lb2, L1_2, L2_2,
        Lb + 40960, Lb + 41984, fc_w, fc_b, cwP2, h, stats);
    mix1_kernel<true><<<dim3(224, 4), 256, 0, stream>>>(h, sm_lg, sm_lb, M1T, stats, A);
  } else {
    s1s<0, false><<<4096, 256, S1_LDS, stream>>>(x, cb0, lg0, lb0, L1_0, L2_0,
        nullptr, nullptr, fc_w, fc_b, cwP0, h, stats);
    s1s<1, false><<<4096, 256, S1_LDS, stream>>>(x, cb1, lg1, lb1, L1_1, L2_1,
        nullptr, nullptr, fc_w, fc_b, cwP1, h, stats);
    s1s<2, false><<<4096, 256, S1_LDS, stream>>>(x, cb2, lg2, lb2, L1_2, L2_2,
        nullptr, nullptr, fc_w, fc_b, cwP2, h, stats);
    mix1_kernel<false><<<dim3(224, 4), 256, 0, stream>>>(h, sm_lg, sm_lb, M1, stats, A);
  }

  out_kernel<<<1024, 256, 0, stream>>>(h, A, M2, sm_fc_w, sm_fc_b, (float*)d_out);
}

// Round 9
// 809.004 us; speedup vs baseline: 1.1781x; 1.1781x over previous
//
#include <hip/hip_runtime.h>
#include <stdint.h>

typedef __attribute__((ext_vector_type(8))) short short8;
typedef __attribute__((ext_vector_type(4))) float f32x4;
typedef __attribute__((ext_vector_type(4))) unsigned short us4;

__device__ __forceinline__ unsigned short f2bf(float f) {
  union { float f; unsigned int i; } v; v.f = f;
  unsigned int r = (v.i + 0x7FFFu + ((v.i >> 16) & 1u)) >> 16;
  return (unsigned short)r;
}
__device__ __forceinline__ float hswish(float x) {
  float t = fminf(fmaxf(x + 3.f, 0.f), 6.f);
  return x * t * (1.f / 6.f);
}

// ---------------------------------------------------------------------------
// Prep: pack conv weights into per-lane-contiguous MFMA fragment order.
// (round-6 version, measured)
// ---------------------------------------------------------------------------
__device__ __forceinline__ void cwprep(const float* __restrict__ cw,
                                       unsigned short* __restrict__ dst,
                                       int rel, int k, int NKS) {
  int e = rel & 7;
  int lane = (rel >> 3) & 63;
  int rest = rel >> 9;
  int ksl = rest % NKS, ot = rest / NKS;
  int m = ksl * 32 + (lane >> 4) * 8 + e;
  int o = ot * 16 + (lane & 15);
  int j = m >> 7, i = m & 127;
  dst[rel] = f2bf(cw[(o * 128 + i) * k + j]);
}

__global__ void prep_kernel(const float* __restrict__ cw0,
                            const float* __restrict__ cw1,
                            const float* __restrict__ cw2,
                            unsigned short* __restrict__ cwP0,
                            unsigned short* __restrict__ cwP1,
                            unsigned short* __restrict__ cwP2) {
  int idx = blockIdx.x * 256 + threadIdx.x;
  if (idx < 16384)       cwprep(cw0, cwP0, idx,          1,  4);
  else if (idx < 49152)  cwprep(cw1, cwP1, idx - 16384,  2,  8);
  else if (idx < 114688) cwprep(cw2, cwP2, idx - 49152,  4, 16);
}

// ---------------------------------------------------------------------------
// L-matrix fragment: gather 8 consecutive fp32, tril-mask, convert to bf16.
// ---------------------------------------------------------------------------
__device__ __forceinline__ short8 lfrag(const float* __restrict__ L, int TK,
                                        int srow, int scol) {
  const float4 v0 = *(const float4*)(L + srow * TK + scol);
  const float4 v1 = *(const float4*)(L + srow * TK + scol + 4);
  short8 r;
  r[0] = (scol     <= srow) ? (short)f2bf(v0.x) : (short)0;
  r[1] = (scol + 1 <= srow) ? (short)f2bf(v0.y) : (short)0;
  r[2] = (scol + 2 <= srow) ? (short)f2bf(v0.z) : (short)0;
  r[3] = (scol + 3 <= srow) ? (short)f2bf(v0.w) : (short)0;
  r[4] = (scol + 4 <= srow) ? (short)f2bf(v1.x) : (short)0;
  r[5] = (scol + 5 <= srow) ? (short)f2bf(v1.y) : (short)0;
  r[6] = (scol + 6 <= srow) ? (short)f2bf(v1.z) : (short)0;
  r[7] = (scol + 7 <= srow) ? (short)f2bf(v1.w) : (short)0;
  return r;
}

// ---------------------------------------------------------------------------
// Conv, o-ownership (round-6 measured version).
// ---------------------------------------------------------------------------
template <int S, int nTT>
__device__ __forceinline__ void conv_o(const unsigned short* __restrict__ xb,
                                       const unsigned short* __restrict__ cwP,
                                       f32x4 (&acc)[nTT][2],
                                       int wave, int lane, int quad, int l16) {
  constexpr int NKS = (128 << S) / 32;
#pragma unroll
  for (int tt = 0; tt < nTT; ++tt)
#pragma unroll
    for (int oo = 0; oo < 2; ++oo)
      acc[tt][oo] = (f32x4){0.f, 0.f, 0.f, 0.f};

#pragma unroll
  for (int ks = 0; ks < NKS; ++ks) {
    const int m = ks * 32 + quad * 8;
    short8 a[nTT];
#pragma unroll
    for (int tt = 0; tt < nTT; ++tt) {
      int t = tt * 16 + l16;
      a[tt] = *(const short8*)&xb[((t << S) + (m >> 7)) * 136 + (m & 127)];
    }
#pragma unroll
    for (int oo = 0; oo < 2; ++oo) {
      const short8 b = *(const short8*)&cwP[(((wave * 2 + oo) * NKS + ks) * 64 + lane) * 8];
#pragma unroll
      for (int tt = 0; tt < nTT; ++tt)
        acc[tt][oo] = __builtin_amdgcn_mfma_f32_16x16x32_bf16(a[tt], b, acc[tt][oo], 0, 0, 0);
    }
  }
}

// ---------------------------------------------------------------------------
// Post (round-6 measured version, single-barrier LN finalize).
// scratch: [0,128) fcw; [128,352) part; [352,360) red
// ---------------------------------------------------------------------------
template <int S, int nTT>
__device__ __forceinline__ void post_o(unsigned short* __restrict__ HT,
                                       float* __restrict__ scratch,
                                       f32x4 (&acc)[nTT][2],
                                       const float* __restrict__ cb,
                                       const float* __restrict__ lg,
                                       const float* __restrict__ lb,
                                       const float* __restrict__ L1,
                                       const float* __restrict__ L2,
                                       int tid, int wave, int lane,
                                       int quad, int l16) {
  constexpr int TK    = 128 >> S;
  constexpr int OFF   = (S == 0) ? 0 : (S == 1 ? 128 : 192);
  constexpr int NTS   = TK / 32;
  constexpr int HTP   = TK + 8;
  constexpr int nTOwn = (S == 0) ? 2 : 1;
  constexpr int nFF   = (S == 2) ? 4 : 8;
  const int ffBase  = (S == 2) ? ((wave >> 1) * 4) : 0;
  const int maxTown = (S == 0) ? (wave + 4) : ((S == 1) ? wave : (wave & 1));

  // ---- +cb, LN stats ----
  float sum = 0.f, ss = 0.f;
#pragma unroll
  for (int oo = 0; oo < 2; ++oo) {
    float cbv = cb[(wave * 2 + oo) * 16 + l16];
#pragma unroll
    for (int tt = 0; tt < nTT; ++tt)
#pragma unroll
      for (int r = 0; r < 4; ++r) {
        float v = acc[tt][oo][r] + cbv;
        acc[tt][oo][r] = v;
        sum += v; ss += v * v;
      }
  }
#pragma unroll
  for (int m = 32; m >= 1; m >>= 1) {
    sum += __shfl_xor(sum, m);
    ss  += __shfl_xor(ss, m);
  }
  if (lane == 0) { scratch[352 + wave * 2] = sum; scratch[353 + wave * 2] = ss; }

  // ---- fc contribution #1 ----
#pragma unroll
  for (int tt = 0; tt < nTT; ++tt)
#pragma unroll
    for (int r = 0; r < 4; ++r) {
      float v = acc[tt][0][r] * scratch[(wave * 2) * 16 + l16]
              + acc[tt][1][r] * scratch[(wave * 2 + 1) * 16 + l16];
      v += __shfl_xor(v, 1); v += __shfl_xor(v, 2);
      v += __shfl_xor(v, 4); v += __shfl_xor(v, 8);
      if (l16 == 0)
        atomicAdd(&scratch[128 + OFF + tt * 16 + quad * 4 + r], v);
    }
  __syncthreads();

  const float Sm = scratch[352] + scratch[354] + scratch[356] + scratch[358];
  const float Sq = scratch[353] + scratch[355] + scratch[357] + scratch[359];
  const float mu = Sm * (1.f / (float)(TK * 128));
  const float rsig = rsqrtf(Sq * (1.f / (float)(TK * 128)) - mu * mu + 1e-5f);

  // ---- HT[f][t] = bf16(LN(h)) ----
#pragma unroll
  for (int oo = 0; oo < 2; ++oo) {
    const int o = (wave * 2 + oo) * 16 + l16;
#pragma unroll
    for (int tt = 0; tt < nTT; ++tt)
#pragma unroll
      for (int r = 0; r < 4; ++r) {
        const int t = tt * 16 + quad * 4 + r;
        float hv = (acc[tt][oo][r] - mu) * rsig * lg[t * 128 + o] + lb[t * 128 + o];
        HT[o * HTP + t] = f2bf(hv);
      }
  }
  __syncthreads();

  // ---- TM1 ----
  f32x4 uacc[nTOwn][nFF];
#pragma unroll
  for (int tt = 0; tt < nTOwn; ++tt)
#pragma unroll
    for (int ff = 0; ff < nFF; ++ff)
      uacc[tt][ff] = (f32x4){0.f, 0.f, 0.f, 0.f};

#pragma unroll
  for (int ks = 0; ks < NTS; ++ks) {
    const int k0 = ks * 32;
    if (k0 <= maxTown * 16 + 15) {
      short8 a[nTOwn];
#pragma unroll
      for (int tt = 0; tt < nTOwn; ++tt) {
        const int tw = (S == 0) ? (wave + tt * 4) : maxTown;
        if (k0 <= tw * 16 + 15)
          a[tt] = lfrag(L1, TK, tw * 16 + l16, k0 + quad * 8);
      }
#pragma unroll
      for (int ff = 0; ff < nFF; ++ff) {
        const short8 b = *(const short8*)&HT[((ffBase + ff) * 16 + l16) * HTP + k0 + quad * 8];
#pragma unroll
        for (int tt = 0; tt < nTOwn; ++tt) {
          const int tw = (S == 0) ? (wave + tt * 4) : maxTown;
          if (k0 <= tw * 16 + 15)
            uacc[tt][ff] = __builtin_amdgcn_mfma_f32_16x16x32_bf16(a[tt], b, uacc[tt][ff], 0, 0, 0);
        }
      }
    }
  }
  __syncthreads();

  // ---- UT = hswish(U) ----
#pragma unroll
  for (int tt = 0; tt < nTOwn; ++tt) {
    const int tw = (S == 0) ? (wave + tt * 4) : maxTown;
#pragma unroll
    for (int ff = 0; ff < nFF; ++ff) {
      const int f = (ffBase + ff) * 16 + l16;
#pragma unroll
      for (int r = 0; r < 4; ++r) {
        const int t = tw * 16 + quad * 4 + r;
        HT[f * HTP + t] = f2bf(hswish(uacc[tt][ff][r]));
      }
    }
  }
  __syncthreads();

  // ---- TM2 ----
#pragma unroll
  for (int tt = 0; tt < nTOwn; ++tt)
#pragma unroll
    for (int ff = 0; ff < nFF; ++ff)
      uacc[tt][ff] = (f32x4){0.f, 0.f, 0.f, 0.f};

#pragma unroll
  for (int ks = 0; ks < NTS; ++ks) {
    const int k0 = ks * 32;
    if (k0 <= maxTown * 16 + 15) {
      short8 a[nTOwn];
#pragma unroll
      for (int tt = 0; tt < nTOwn; ++tt) {
        const int tw = (S == 0) ? (wave + tt * 4) : maxTown;
        if (k0 <= tw * 16 + 15)
          a[tt] = lfrag(L2, TK, tw * 16 + l16, k0 + quad * 8);
      }
#pragma unroll
      for (int ff = 0; ff < nFF; ++ff) {
        const short8 b = *(const short8*)&HT[((ffBase + ff) * 16 + l16) * HTP + k0 + quad * 8];
#pragma unroll
        for (int tt = 0; tt < nTOwn; ++tt) {
          const int tw = (S == 0) ? (wave + tt * 4) : maxTown;
          if (k0 <= tw * 16 + 15)
            uacc[tt][ff] = __builtin_amdgcn_mfma_f32_16x16x32_bf16(a[tt], b, uacc[tt][ff], 0, 0, 0);
        }
      }
    }
  }

  // ---- fc contribution #2 ----
#pragma unroll
  for (int tt = 0; tt < nTOwn; ++tt) {
    const int tw = (S == 0) ? (wave + tt * 4) : maxTown;
#pragma unroll
    for (int r = 0; r < 4; ++r) {
      float v = 0.f;
#pragma unroll
      for (int ff = 0; ff < nFF; ++ff)
        v += uacc[tt][ff][r] * scratch[(ffBase + ff) * 16 + l16];
      v += __shfl_xor(v, 1); v += __shfl_xor(v, 2);
      v += __shfl_xor(v, 4); v += __shfl_xor(v, 8);
      if (l16 == 0)
        atomicAdd(&scratch[128 + OFF + tw * 16 + quad * 4 + r], v);
    }
  }
}

// ---------------------------------------------------------------------------
// Fused stage 1 (round-6 measured version: 455 µs).
// ---------------------------------------------------------------------------
__launch_bounds__(256, 2)
__global__ void s1_fused(const float* __restrict__ x,
                         const float* __restrict__ cb0, const float* __restrict__ lg0,
                         const float* __restrict__ lb0, const float* __restrict__ L1_0,
                         const float* __restrict__ L2_0,
                         const float* __restrict__ cb1, const float* __restrict__ lg1,
                         const float* __restrict__ lb1, const float* __restrict__ L1_1,
                         const float* __restrict__ L2_1,
                         const float* __restrict__ cb2, const float* __restrict__ lg2,
                         const float* __restrict__ lb2, const float* __restrict__ L1_2,
                         const float* __restrict__ L2_2,
                         const float* __restrict__ fc_w, const float* __restrict__ fc_b,
                         const unsigned short* __restrict__ cwP0,
                         const unsigned short* __restrict__ cwP1,
                         const unsigned short* __restrict__ cwP2,
                         float* __restrict__ h_out,
                         float* __restrict__ stats) {
  extern __shared__ char smem[];
  unsigned short* xb = (unsigned short*)smem;         // 128 x 136 bf16
  float* scratch = (float*)(smem + 34816);

  const int tid  = threadIdx.x;
  const int wave = tid >> 6;
  const int lane = tid & 63;
  const int quad = lane >> 4;
  const int l16  = lane & 15;
  const int n    = blockIdx.x;
  const float* xn = x + (size_t)n * 16384;

  if (tid < 128) scratch[tid] = fc_w[tid];
  if (tid < 224) scratch[128 + tid] = 0.f;

  for (int i = tid; i < 4096; i += 256) {
    int t = i >> 5, c4 = (i & 31) * 4;
    const float4 v = *(const float4*)(xn + t * 128 + c4);
    us4 p; p[0] = f2bf(v.x); p[1] = f2bf(v.y); p[2] = f2bf(v.z); p[3] = f2bf(v.w);
    *(us4*)&xb[t * 136 + c4] = p;
  }
  __syncthreads();

  f32x4 acc0[8][2], acc1[4][2], acc2[2][2];
  conv_o<0, 8>(xb, cwP0, acc0, wave, lane, quad, l16);
  conv_o<1, 4>(xb, cwP1, acc1, wave, lane, quad, l16);
  conv_o<2, 2>(xb, cwP2, acc2, wave, lane, quad, l16);

  unsigned short* HT = xb;
  post_o<2, 2>(HT, scratch, acc2, cb2, lg2, lb2, L1_2, L2_2, tid, wave, lane, quad, l16);
  post_o<1, 4>(HT, scratch, acc1, cb1, lg1, lb1, L1_1, L2_1, tid, wave, lane, quad, l16);
  post_o<0, 8>(HT, scratch, acc0, cb0, lg0, lb0, L1_0, L2_0, tid, wave, lane, quad, l16);

  __syncthreads();

  float hv = 0.f;
  if (tid < 224) {
    hv = scratch[128 + tid] + fc_b[0];
    h_out[(size_t)n * 224 + tid] = hv;
  }
  float s = hv, sq = hv * hv;
#pragma unroll
  for (int m = 32; m >= 1; m >>= 1) {
    s  += __shfl_xor(s, m);
    sq += __shfl_xor(sq, m);
  }
  __syncthreads();
  if (lane == 0) { scratch[352 + wave * 2] = s; scratch[353 + wave * 2] = sq; }
  __syncthreads();
  if (tid == 0) {
    atomicAdd(&stats[0], scratch[352] + scratch[354] + scratch[356] + scratch[358]);
    atomicAdd(&stats[1], scratch[353] + scratch[355] + scratch[357] + scratch[359]);
  }
}

// ---------------------------------------------------------------------------
// mix1 with in-block LDS transpose of M1 (fixes the 16x line amplification
// that made the old lane-scattered M1[r*4096+n] read cost ~14 GB of L2
// traffic). M1 tiles loaded coalesced, consumed via padded LDS (stride 65
// -> conflict-free). Double-buffered: one barrier per 64-n chunk.
// A stored transposed: A[m*64 + r].
// ---------------------------------------------------------------------------
__global__ void mix1_kernel(const float* __restrict__ h,
                            const float* __restrict__ sm_lg,
                            const float* __restrict__ sm_lb,
                            const float* __restrict__ M1,
                            const float* __restrict__ stats,
                            float* __restrict__ A) {
  const int m = blockIdx.x;            // 0..223
  const int seg = blockIdx.y;          // 0..3
  const int tid = threadIdx.x;
  const int wave = tid >> 6;
  const int lane = tid & 63;

  __shared__ float tile[2][64 * 65];
  __shared__ float red[256];

  const float inv = 1.f / 917504.f;
  const float mu = stats[0] * inv;
  const float var = stats[1] * inv - mu * mu;
  const float rsig = rsqrtf(var + 1e-5f);

  // thread's slice of each 64x64 M1 tile: row rr, 16 cols starting at cbase
  const int rr = tid >> 2;
  const int cbase = (tid & 3) * 16;

  float acc = 0.f;
  for (int c = 0; c < 16; ++c) {
    const int n0 = seg * 1024 + c * 64;
    float* tl = tile[c & 1];
    // coalesced load of M1[rr][n0 + cbase .. +16) -> LDS (transpose-ready)
#pragma unroll
    for (int i = 0; i < 4; ++i) {
      const float4 v = *(const float4*)(M1 + rr * 4096 + n0 + cbase + i * 4);
      tl[rr * 65 + cbase + i * 4    ] = v.x;
      tl[rr * 65 + cbase + i * 4 + 1] = v.y;
      tl[rr * 65 + cbase + i * 4 + 2] = v.z;
      tl[rr * 65 + cbase + i * 4 + 3] = v.w;
    }
    __syncthreads();
    // wave w consumes n-sub [w*16, w*16+16); lane = r
#pragma unroll
    for (int j = 0; j < 16; ++j) {
      const int nn = wave * 16 + j;
      const int n = n0 + nn;
      const float hn = (h[n * 224 + m] - mu) * rsig * sm_lg[n * 224 + m] + sm_lb[n * 224 + m];
      acc += tl[lane * 65 + nn] * hn;
    }
  }
  red[tid] = acc;
  __syncthreads();
  if (tid < 64)
    atomicAdd(&A[m * 64 + tid],
              red[tid] + red[64 + tid] + red[128 + tid] + red[192 + tid]);
}

// out_kernel with mix2 fused; A transposed [m][r] -> coalesced reads.
__global__ void out_kernel(const float* __restrict__ h,
                           const float* __restrict__ A,
                           const float* __restrict__ M2,
                           const float* __restrict__ sm_fc_w,
                           const float* __restrict__ sm_fc_b,
                           float* __restrict__ out) {
  const int tid = threadIdx.x;
  const int wave = tid >> 6, lane = tid & 63;
  __shared__ float red[256];
  __shared__ float cv[64];

  // cvec[r] = sum_j hswish(A[j][r]) * sm_fc_w[224+j]
  {
    const int r = tid & 63, ch = tid >> 6;
    float acc = 0.f;
    for (int j = ch; j < 224; j += 4)
      acc += hswish(A[j * 64 + r]) * sm_fc_w[224 + j];
    red[tid] = acc;
  }
  __syncthreads();
  if (tid < 64)
    cv[tid] = red[tid] + red[64 + tid] + red[128 + tid] + red[192 + tid];
  __syncthreads();

  const int n = blockIdx.x * 4 + wave;
  float acc = M2[n * 64 + lane] * cv[lane];
  for (int j = lane; j < 224; j += 64)
    acc += h[n * 224 + j] * (sm_fc_w[j] + sm_fc_w[224 + j]);
#pragma unroll
  for (int m = 32; m >= 1; m >>= 1) acc += __shfl_xor(acc, m);
  if (lane == 0) out[n] = acc + sm_fc_b[0];
}

// ---------------------------------------------------------------------------
extern "C" void kernel_launch(void* const* d_in, const int* in_sizes, int n_in,
                              void* d_out, int out_size, void* d_ws, size_t ws_size,
                              hipStream_t stream) {
  const float* x      = (const float*)d_in[0];
  const float* cw0    = (const float*)d_in[1];
  const float* cb0    = (const float*)d_in[2];
  const float* lg0    = (const float*)d_in[3];
  const float* lb0    = (const float*)d_in[4];
  const float* L1_0   = (const float*)d_in[5];
  const float* L2_0   = (const float*)d_in[6];
  const float* cw1    = (const float*)d_in[7];
  const float* cb1    = (const float*)d_in[8];
  const float* lg1    = (const float*)d_in[9];
  const float* lb1    = (const float*)d_in[10];
  const float* L1_1   = (const float*)d_in[11];
  const float* L2_1   = (const float*)d_in[12];
  const float* cw2    = (const float*)d_in[13];
  const float* cb2    = (const float*)d_in[14];
  const float* lg2    = (const float*)d_in[15];
  const float* lb2    = (const float*)d_in[16];
  const float* L1_2   = (const float*)d_in[17];
  const float* L2_2   = (const float*)d_in[18];
  const float* fc_w   = (const float*)d_in[19];
  const float* fc_b   = (const float*)d_in[20];
  const float* sm_lg  = (const float*)d_in[21];
  const float* sm_lb  = (const float*)d_in[22];
  const float* M1     = (const float*)d_in[23];
  const float* M2     = (const float*)d_in[24];
  const float* sm_fc_w = (const float*)d_in[25];
  const float* sm_fc_b = (const float*)d_in[26];

  // Proven workspace footprint (3,957,248 B) — no optional regions.
  char* ws = (char*)d_ws;
  unsigned short* cwP0 = (unsigned short*)(ws);             // 32768 B
  unsigned short* cwP1 = (unsigned short*)(ws + 32768);     // 65536 B
  unsigned short* cwP2 = (unsigned short*)(ws + 98304);     // 131072 B
  float* h     = (float*)(ws + 229376);                     // 3670016 B
  float* stats = (float*)(ws + 3899392);                    // 8 B
  float* A     = (float*)(ws + 3899648);                    // 57344 B (A^T [224][64])

  prep_kernel<<<448, 256, 0, stream>>>(cw0, cw1, cw2, cwP0, cwP1, cwP2);

  // zero stats + A BEFORE s1 (s1's epilogue atomicAdds into stats)
  hipMemsetAsync(ws + 3899392, 0, 57600, stream);

  constexpr size_t S1_LDS = 34816 + 362 * 4;   // xb/HT union + scratch = 36264 B

  s1_fused<<<4096, 256, S1_LDS, stream>>>(
      x,
      cb0, lg0, lb0, L1_0, L2_0,
      cb1, lg1, lb1, L1_1, L2_1,
      cb2, lg2, lb2, L1_2, L2_2,
      fc_w, fc_b, cwP0, cwP1, cwP2, h, stats);

  mix1_kernel<<<dim3(224, 4), 256, 0, stream>>>(h, sm_lg, sm_lb, M1, stats, A);
  out_kernel<<<1024, 256, 0, stream>>>(h, A, M2, sm_fc_w, sm_fc_b, (float*)d_out);
}